// Round 6
// baseline (286.028 us; speedup 1.0000x reference)
//
#include <hip/hip_runtime.h>
#include <math.h>

#define BS   2048
#define SEQ  50
#define NPOS (BS * SEQ)

typedef __attribute__((ext_vector_type(8))) short bf16x8;   // 8 bf16 = 4 VGPR
typedef __attribute__((ext_vector_type(4))) float f32x4;

__device__ __forceinline__ float sigf(float x) { return 1.0f / (1.0f + __expf(-x)); }
__device__ __forceinline__ float tanhfast(float x) {
    float e = __expf(2.0f * x);
    return 1.0f - 2.0f / (e + 1.0f);
}
__device__ __forceinline__ unsigned short bfrn(float x) {   // fp32 -> bf16 rne
    unsigned int u = __float_as_uint(x);
    u += 0x7FFFu + ((u >> 16) & 1u);
    return (unsigned short)(u >> 16);
}
__device__ __forceinline__ float bf2f(unsigned short h) {
    return __uint_as_float(((unsigned int)h) << 16);
}

#define FMA4(A, X, W) \
    A = fmaf((X).x, (W).x, A); A = fmaf((X).y, (W).y, A); \
    A = fmaf((X).z, (W).z, A); A = fmaf((X).w, (W).w, A);

// ---------------------------------------------------------------------------
// Precomputed attention tables (position-independent, built by prep kernel):
//   Wvf[64][10]: Wv . Wf(:,0:10)
//   Ce [64][9]:  (Wf(:,10+e)+bf) . Wv
//   Ag [4][10][7]: g_h[k] = Ag[h][k][0:6].self6 + Ag[h][k][6]
//                  (key phase folded: Ag = G^T Wk / G^T bk)
//   Bd [9][4][7]:  dd[e][h] = Bd[e][h][0:6].self6 + Bd[e][h][6]
// Per position:  att[e][h] = 0.25*(raw10_e . g_h + dd[e][h]), softmax,
//                ctx[o] = (rbar_h . Wvf[o] + sum_e p Ce'[o][e]) (Ce' incl bv)
// ---------------------------------------------------------------------------
__device__ float Wvf_d[640];
__device__ float Ce_d[576];
__device__ float Ag_d[280];
__device__ float Bd_d[252];

// ---------------------------------------------------------------------------
// prep: blocks 0..47 build MFMA weight fragments; blocks 48..51 attn tables.
// ---------------------------------------------------------------------------
__global__ __launch_bounds__(512) void prep_all(
    const float* __restrict__ Wih, const float* __restrict__ Whh,
    bf16x8* __restrict__ whF, bf16x8* __restrict__ wiF,
    const float* __restrict__ Wf, const float* __restrict__ bf,
    const float* __restrict__ Wq, const float* __restrict__ bq,
    const float* __restrict__ Wv,
    const float* __restrict__ Wk, const float* __restrict__ bk)
{
    int id = blockIdx.x * 512 + threadIdx.x;
    if (id < 24576) {
        const float* src;
        bf16x8* dst;
        int p;
        if (id < 16384) {
            int l = id & 63, frag = id >> 6;        // 0..255
            p = frag & 1;
            int kc = (frag >> 1) & 3, ti = (frag >> 3) & 3, w = frag >> 5;
            int n  = (w + 8 * ti) * 16 + (l & 15);
            int k0 = kc * 32 + (l >> 4) * 8;
            src = &Whh[n * 128 + k0];
            dst = &whF[frag * 64 + l];
        } else {
            int id2 = id - 16384;
            int l = id2 & 63, frag = id2 >> 6;      // 0..127
            p = frag & 1;
            int kc = (frag >> 1) & 1, tile = frag >> 2;
            int n  = tile * 16 + (l & 15);
            int k0 = kc * 32 + (l >> 4) * 8;
            src = &Wih[n * 64 + k0];
            dst = &wiF[frag * 64 + l];
        }
        bf16x8 v;
        #pragma unroll
        for (int j = 0; j < 8; ++j) {
            float x = src[j];
            unsigned short hi = bfrn(x);
            unsigned short r  = p ? bfrn(x - bf2f(hi)) : hi;
            v[j] = (short)r;
        }
        *dst = v;
        return;
    }
    int i = id - 24576;
    if (i >= 1748) return;
    if (i < 640) {                       // Wvf[o][k]
        int o = i / 10, k = i % 10;
        float s = 0.f;
        #pragma unroll 8
        for (int j = 0; j < 64; ++j) s = fmaf(Wv[o * 64 + j], Wf[j * 19 + k], s);
        Wvf_d[i] = s;
    } else if (i < 1216) {               // Ce[o][e]
        int i2 = i - 640;
        int o = i2 / 9, e = i2 % 9;
        float s = 0.f;
        #pragma unroll 8
        for (int j = 0; j < 64; ++j)
            s = fmaf(Wf[j * 19 + 10 + e] + bf[j], Wv[o * 64 + j], s);
        Ce_d[i2] = s;
    } else if (i < 1496) {               // Ag[h][k][j]
        int i3 = i - 1216;               // 0..279
        int h = i3 / 70, rem = i3 % 70, k = rem / 7, j = rem % 7;
        float s = 0.f;
        for (int d = 0; d < 16; ++d) {
            int n = h * 16 + d;
            float Gnk = 0.f;
            #pragma unroll 8
            for (int mm = 0; mm < 64; ++mm)
                Gnk = fmaf(Wq[n * 64 + mm], Wf[mm * 19 + k], Gnk);
            float wkj = (j < 6) ? Wk[n * 6 + j] : bk[n];
            s = fmaf(wkj, Gnk, s);
        }
        Ag_d[i3] = s;
    } else {                             // Bd[e][h][j]
        int i4 = i - 1496;               // 0..251
        int e = i4 / 28, rem = i4 % 28, h = rem / 7, j = rem % 7;
        float s = 0.f;
        for (int d = 0; d < 16; ++d) {
            int n = h * 16 + d;
            float Den = bq[n];
            #pragma unroll 8
            for (int mm = 0; mm < 64; ++mm)
                Den = fmaf(Wf[mm * 19 + 10 + e] + bf[mm], Wq[n * 64 + mm], Den);
            float wkj = (j < 6) ? Wk[n * 6 + j] : bk[n];
            s = fmaf(wkj, Den, s);
        }
        Bd_d[i4] = s;
    }
}

// ---------------------------------------------------------------------------
// Kernel A v3: wave-synchronous attention.
//  - key phase folded into Ag/Bd tables (affine in self6): one fewer phase,
//    ~26 fewer FMA/lane, table regs 32 -> 14.
//  - NO __syncthreads: each stream is ONE wave; same-wave DS ops are FIFO in
//    the LDS pipe, so cross-lane LDS visibility needs only a compiler
//    ordering fence (__builtin_amdgcn_wave_barrier, zero instructions).
//  - 128-thr blocks = 2 independent wave-streams (disjoint LDS slices);
//    4096 blocks -> 8192 streams x 12-13 positions; launch_bounds(128,6)
//    -> up to 24 waves/CU (was 16).
// ---------------------------------------------------------------------------
__global__ __launch_bounds__(128, 6) void edge_attn_ctx(
    const float* __restrict__ seqs,   // [BS,SEQ,3,3,6]
    const float* __restrict__ ets,    // [BS,SEQ,3,3,4]
    const int*   __restrict__ masks,  // [BS,SEQ,3,3]
    const float* __restrict__ bv,
    float* __restrict__ ctx)          // [BS,SEQ,64]
{
    const int wid = threadIdx.x >> 6;
    const int o   = threadIdx.x & 63;
    const int h_o = o >> 4;
    const int lg  = (o < 40) ? o : 0;     // g/rbar lanes: (gh, gk)
    const int gh  = lg / 10, gk = lg % 10;
    const int la  = (o < 36) ? o : 0;     // att lanes: (ah, ae)
    const int ah  = la / 9,  ae = la % 9;

    float Agr[7], Bdr[7];
    #pragma unroll
    for (int j = 0; j < 7; ++j) Agr[j] = Ag_d[(gh * 10 + gk) * 7 + j];
    #pragma unroll
    for (int j = 0; j < 7; ++j) Bdr[j] = Bd_d[(ae * 4 + ah) * 7 + j];
    float Wvfr[10];
    #pragma unroll
    for (int k = 0; k < 10; ++k) Wvfr[k] = Wvf_d[o * 10 + k];
    const float bvr = bv[o];
    float Cer[9];
    #pragma unroll
    for (int e = 0; e < 9; ++e) Cer[e] = Ce_d[o * 9 + e] + bvr;

    __shared__ float s_seq[2][54], s_et[2][36], s_g[2][40];
    __shared__ float s_att[2][36], s_exp[2][36], s_rbar[2][40];
    __shared__ int   s_mask[2][9];
    float* sq = s_seq[wid];  float* se = s_et[wid];  float* sg = s_g[wid];
    float* sa = s_att[wid];  float* sx = s_exp[wid]; float* sr = s_rbar[wid];
    int*   sm = s_mask[wid];

    const int stream = blockIdx.x * 2 + wid;   // 0..8191

    float r_seq = 0.f, r_et = 0.f; int r_mask = 0;
    if (o < 54) r_seq  = seqs[stream * 54 + o];
    if (o < 36) r_et   = ets[stream * 36 + o];
    if (o < 9)  r_mask = masks[stream * 9 + o];

    for (int p = stream; p < NPOS; p += 8192) {
        // ---- stage (from prefetched regs) ----
        if (o < 54) sq[o] = r_seq;
        if (o < 36) se[o] = r_et;
        if (o < 9)  sm[o] = r_mask;
        __builtin_amdgcn_wave_barrier();

        // ---- issue next-position prefetch ----
        {
            int pn = p + 8192;
            if (pn < NPOS) {
                if (o < 54) r_seq  = seqs[pn * 54 + o];
                if (o < 36) r_et   = ets[pn * 36 + o];
                if (o < 9)  r_mask = masks[pn * 9 + o];
            }
        }

        // ---- g (lanes<40) and dd (lanes<36) from self6 broadcast ----
        float c0 = sq[24], c1 = sq[25], c2 = sq[26],
              c3 = sq[27], c4 = sq[28], c5 = sq[29];
        float tt = 0.f;
        if (o < 40) {
            float g = Agr[6];
            g = fmaf(c0, Agr[0], g); g = fmaf(c1, Agr[1], g);
            g = fmaf(c2, Agr[2], g); g = fmaf(c3, Agr[3], g);
            g = fmaf(c4, Agr[4], g); g = fmaf(c5, Agr[5], g);
            sg[o] = g;
        }
        if (o < 36) {
            tt = Bdr[6];
            tt = fmaf(c0, Bdr[0], tt); tt = fmaf(c1, Bdr[1], tt);
            tt = fmaf(c2, Bdr[2], tt); tt = fmaf(c3, Bdr[3], tt);
            tt = fmaf(c4, Bdr[4], tt); tt = fmaf(c5, Bdr[5], tt);
        }
        __builtin_amdgcn_wave_barrier();

        // ---- att[e][h] (lanes<36) ----
        float a = 0.f;
        if (o < 36) {
            a = tt;
            #pragma unroll
            for (int k = 0; k < 6; ++k) a = fmaf(sq[ae * 6 + k], sg[ah * 10 + k], a);
            #pragma unroll
            for (int k = 0; k < 4; ++k) a = fmaf(se[ae * 4 + k], sg[ah * 10 + 6 + k], a);
            a *= 0.25f;
            if (sm[ae] == 0) a = -1.0e10f;
            sa[o] = a;
        }
        __builtin_amdgcn_wave_barrier();

        // ---- exp with per-head max (lanes<36) ----
        float ex = 0.f;
        if (o < 36) {
            float mx = sa[ah * 9 + 0];
            #pragma unroll
            for (int e = 1; e < 9; ++e) mx = fmaxf(mx, sa[ah * 9 + e]);
            ex = __expf(a - mx);
            sx[o] = ex;
        }
        __builtin_amdgcn_wave_barrier();

        // ---- rbar (lanes<40, unnormalized) ----
        if (o < 40) {
            float rb = 0.f;
            #pragma unroll
            for (int e = 0; e < 9; ++e) {
                float x = (gk < 6) ? sq[e * 6 + gk] : se[e * 4 + (gk - 6)];
                rb = fmaf(sx[gh * 9 + e], x, rb);
            }
            sr[o] = rb;
        }
        __builtin_amdgcn_wave_barrier();

        // ---- ctx (all 64 lanes) ----
        {
            float ssum = 0.f;
            #pragma unroll
            for (int e = 0; e < 9; ++e) ssum += sx[h_o * 9 + e];
            float acc = 0.f;
            #pragma unroll
            for (int k = 0; k < 10; ++k) acc = fmaf(sr[h_o * 10 + k], Wvfr[k], acc);
            #pragma unroll
            for (int e = 0; e < 9; ++e) acc = fmaf(sx[h_o * 9 + e], Cer[e], acc);
            ctx[p * 64 + o] = acc * (1.0f / ssum);
        }
        __builtin_amdgcn_wave_barrier();
    }
}

// ---------------------------------------------------------------------------
// Kernel C v12: pair-step MFMA LSTM (unchanged from R4; ~115 us).
// ---------------------------------------------------------------------------
#define MFMA16(A, B, C) __builtin_amdgcn_mfma_f32_16x16x32_bf16(A, B, C, 0, 0, 0)
#define MM4(F, W0, W1, W2, W3) \
    a0 = MFMA16(F, W0, a0); a1 = MFMA16(F, W1, a1); \
    a2 = MFMA16(F, W2, a2); a3 = MFMA16(F, W3, a3);

#define HPASS \
    MM4(hfh[0], whr[0][0][0], whr[1][0][0], whr[2][0][0], whr[3][0][0]) \
    MM4(hfh[1], whr[0][1][0], whr[1][1][0], whr[2][1][0], whr[3][1][0]) \
    MM4(hfh[2], whr[0][2][0], whr[1][2][0], whr[2][2][0], whr[3][2][0]) \
    MM4(hfh[3], whr[0][3][0], whr[1][3][0], whr[2][3][0], whr[3][3][0]) \
    MM4(hfl[0], whr[0][0][0], whr[1][0][0], whr[2][0][0], whr[3][0][0]) \
    MM4(hfl[1], whr[0][1][0], whr[1][1][0], whr[2][1][0], whr[3][1][0]) \
    MM4(hfl[2], whr[0][2][0], whr[1][2][0], whr[2][2][0], whr[3][2][0]) \
    MM4(hfl[3], whr[0][3][0], whr[1][3][0], whr[2][3][0], whr[3][3][0]) \
    MM4(hfh[0], whr[0][0][1], whr[1][0][1], whr[2][0][1], whr[3][0][1]) \
    MM4(hfh[1], whr[0][1][1], whr[1][1][1], whr[2][1][1], whr[3][1][1]) \
    MM4(hfh[2], whr[0][2][1], whr[1][2][1], whr[2][2][1], whr[3][2][1]) \
    MM4(hfh[3], whr[0][3][1], whr[1][3][1], whr[2][3][1], whr[3][3][1])

#define REDIST_E(ch, g0, g1) { \
    float s2_ = __shfl_xor(ch[2], 32), s3_ = __shfl_xor(ch[3], 32); \
    g0 = lolq ? ch[0] : s2_;  g1 = lolq ? ch[1] : s3_; }
#define REDIST_O(ch, g0, g1) { \
    float s0_ = __shfl_xor(ch[0], 32), s1_ = __shfl_xor(ch[1], 32); \
    g0 = lolq ? s0_ : ch[2];  g1 = lolq ? s1_ : ch[3]; }

#define PWBODY(gi0,gf0,gg0,go0,gi1,gf1,gg1,go1, WB0, WB1) { \
    float i0_ = sigf(gi0 + bi), f0_ = sigf(gf0 + bff); \
    float gA_ = tanhfast(gg0 + bg), o0_ = sigf(go0 + bo); \
    c20 = fmaf(f0_, c20, i0_ * gA_); \
    float hv0_ = o0_ * tanhfast(c20); \
    float i1_ = sigf(gi1 + bi), f1_ = sigf(gf1 + bff); \
    float gB_ = tanhfast(gg1 + bg), o1_ = sigf(go1 + bo); \
    c21 = fmaf(f1_, c21, i1_ * gB_); \
    float hv1_ = o1_ * tanhfast(c21); \
    unsigned short hh0_ = bfrn(hv0_), hh1_ = bfrn(hv1_); \
    unsigned short hl0_ = bfrn(hv0_ - bf2f(hh0_)), hl1_ = bfrn(hv1_ - bf2f(hh1_)); \
    *(unsigned short*)((char*)s_hh + (WB0)) = hh0_; \
    *(unsigned short*)((char*)s_hl + (WB0)) = hl0_; \
    *(unsigned short*)((char*)s_hh + (WB1)) = hh1_; \
    *(unsigned short*)((char*)s_hl + (WB1)) = hl1_; }

__global__ __launch_bounds__(512, 2) void lstm_mfma(
    const float*  __restrict__ ctx,    // [BS,SEQ,64]
    const bf16x8* __restrict__ whF,    // 16384 frags
    const bf16x8* __restrict__ wiFg,   // 8192 frags
    const float*  __restrict__ b_ih, const float* __restrict__ b_hh,
    const float*  __restrict__ W_out, const float* __restrict__ b_out,
    float* __restrict__ out)           // [BS,64]
{
    const int t  = threadIdx.x;
    const int w  = t >> 6, l = t & 63;
    const int lm = l & 15, lq = l >> 4;
    const int row0 = blockIdx.x * 8;            // 8 real rows per block

    __shared__ bf16x8 s_wi[8192];                       // 128 KB  W_ih frags
    __shared__ unsigned short s_xh[1024], s_xl[1024];   // [16][64] pair tile
    __shared__ unsigned short s_hh[4096], s_hl[4096];   // planes L(0B) H(4096B)

    for (int i = t; i < 8192; i += 512) s_wi[i] = wiFg[i];
    for (int i = t; i < 1024; i += 512) { s_xh[i] = 0; s_xl[i] = 0; }
    for (int i = t; i < 4096; i += 512) { s_hh[i] = 0; s_hl[i] = 0; }

    bf16x8 whr[4][4][2];
    #pragma unroll
    for (int ti = 0; ti < 4; ++ti)
        #pragma unroll
        for (int kc = 0; kc < 4; ++kc)
            #pragma unroll
            for (int p = 0; p < 2; ++p)
                whr[ti][kc][p] = whF[(((w * 4 + ti) * 4 + kc) * 2 + p) * 64 + l];

    const int m = w * 16 + lm;
    const float bi  = b_ih[m]       + b_hh[m];
    const float bff = b_ih[128 + m] + b_hh[128 + m];
    const float bg  = b_ih[256 + m] + b_hh[256 + m];
    const float bo  = b_ih[384 + m] + b_hh[384 + m];

    const int  urb  = ((lq & 1) << 2) | (lq & 2);
    const bool lolq = (lq < 2);
    float c20 = 0.f, c21 = 0.f;

    const int xrow  = t >> 5;
    const int xl32  = t & 31;
    const int srow  = xrow & 7;
    const int spair = xrow >> 3;
    const float2* ctx2 = (const float2*)ctx;
    const int xbase = (row0 + srow) * SEQ + spair;
    const int xwb   = xrow * 128 + ((4 * xl32) ^ ((xrow & 7) << 4));
    const int swzr  = (lm & 7) << 4;
    const int hwb_m = 32 * w + 2 * lm;
    const int wb0e = 4096 + (8 + urb) * 256 + (hwb_m ^ (urb << 4));
    const int wb1e = 4096 + (9 + urb) * 256 + (hwb_m ^ ((urb + 1) << 4));
    const int wb0o = urb * 256 + (hwb_m ^ (urb << 4));
    const int wb1o = (urb + 1) * 256 + (hwb_m ^ ((urb + 1) << 4));

    float2 xv = ctx2[xbase * 32 + xl32];

    for (int u = 0; u < SEQ / 2; ++u) {
        {   // stage x-pair (rows 0-7 = x(s0), rows 8-15 = x(s1))
            unsigned short xh0 = bfrn(xv.x), xh1 = bfrn(xv.y);
            unsigned short xl0 = bfrn(xv.x - bf2f(xh0)), xl1 = bfrn(xv.y - bf2f(xh1));
            *(unsigned int*)((char*)s_xh + xwb) = (unsigned int)xh0 | ((unsigned int)xh1 << 16);
            *(unsigned int*)((char*)s_xl + xwb) = (unsigned int)xl0 | ((unsigned int)xl1 << 16);
        }
        __syncthreads();   // x-pair + h(s0-1) (plane L) visible

        float2 xvn = make_float2(0.f, 0.f);
        if (u + 1 < SEQ / 2) xvn = ctx2[(xbase + 2 * u + 2) * 32 + xl32];

        bf16x8 hfh[4], hfl[4];
        if (u > 0) {
            #pragma unroll
            for (int kc = 0; kc < 4; ++kc) {
                int b = lm * 256 + ((kc * 64 + lq * 16) ^ swzr);   // plane L
                hfh[kc] = *(const bf16x8*)((const char*)s_hh + b);
                hfl[kc] = *(const bf16x8*)((const char*)s_hl + b);
            }
        }
        bf16x8 xfh[2], xfl[2];
        #pragma unroll
        for (int kc = 0; kc < 2; ++kc) {
            int b = lm * 128 + ((kc * 64 + lq * 16) ^ swzr);
            xfh[kc] = *(const bf16x8*)((const char*)s_xh + b);
            xfl[kc] = *(const bf16x8*)((const char*)s_xl + b);
        }

        f32x4 a0 = {0.f,0.f,0.f,0.f}, a1 = a0, a2 = a0, a3 = a0;

        if (u > 0) { HPASS }           // h(s0-1)W -> acc rows 0-7 only

        #pragma unroll                  // x-pass: both steps, junk-free
        for (int kc = 0; kc < 2; ++kc) {
            bf16x8 wihi[4], wilo[4];
            #pragma unroll
            for (int ti = 0; ti < 4; ++ti) {
                int base = (((w + 8 * ti) * 2 + kc) * 2) * 64 + l;
                wihi[ti] = s_wi[base];
                wilo[ti] = s_wi[base + 64];
            }
            MM4(xfh[kc], wihi[0], wihi[1], wihi[2], wihi[3])
            MM4(xfl[kc], wihi[0], wihi[1], wihi[2], wihi[3])
            MM4(xfh[kc], wilo[0], wilo[1], wilo[2], wilo[3])
        }

        {   // even pointwise: rows 0-7
            float gi0, gi1, gf0, gf1, gg0, gg1, go0, go1;
            REDIST_E(a0, gi0, gi1)
            REDIST_E(a1, gf0, gf1)
            REDIST_E(a2, gg0, gg1)
            REDIST_E(a3, go0, go1)
            PWBODY(gi0, gf0, gg0, go0, gi1, gf1, gg1, go1, wb0e, wb1e)
        }

        // ================= ODD step s1 = 2u+1 =================
        __syncthreads();   // h(s0) (plane H) visible
        #pragma unroll
        for (int kc = 0; kc < 4; ++kc) {
            int b = 4096 + lm * 256 + ((kc * 64 + lq * 16) ^ swzr);  // plane H
            hfh[kc] = *(const bf16x8*)((const char*)s_hh + b);
            hfl[kc] = *(const bf16x8*)((const char*)s_hl + b);
        }
        HPASS                          // h(s0)W -> acc rows 8-15 only

        {   // odd pointwise: rows 8-15
            float gi0, gi1, gf0, gf1, gg0, gg1, go0, go1;
            REDIST_O(a0, gi0, gi1)
            REDIST_O(a1, gf0, gf1)
            REDIST_O(a2, gg0, gg1)
            REDIST_O(a3, go0, go1)
            PWBODY(gi0, gf0, gg0, go0, gi1, gf1, gg1, go1, wb0o, wb1o)
        }
        xv = xvn;
    }
    __syncthreads();

    // ---- epilogue: h(SEQ-1)=h(49) is odd -> plane L rows 0-7 ----
    {
        const int row = t >> 5;
        if (row < 8) {
            const int j0 = t & 31, j1 = (t & 31) + 32;
            const int rswz = (row & 7) << 4;
            float accA = b_out[j0], accB = b_out[j1];
            #pragma unroll
            for (int kq = 0; kq < 16; ++kq) {
                int b = row * 256 + ((kq * 16) ^ rswz);
                bf16x8 hh8 = *(const bf16x8*)((const char*)s_hh + b);
                bf16x8 hl8 = *(const bf16x8*)((const char*)s_hl + b);
                #pragma unroll
                for (int e = 0; e < 8; ++e) {
                    float h = bf2f((unsigned short)hh8[e]) + bf2f((unsigned short)hl8[e]);
                    int k = kq * 8 + e;
                    accA = fmaf(h, W_out[j0 * 128 + k], accA);
                    accB = fmaf(h, W_out[j1 * 128 + k], accB);
                }
            }
            out[(row0 + row) * 64 + j0] = accA;
            out[(row0 + row) * 64 + j1] = accB;
        }
    }
}

// ---------------------------------------------------------------------------
extern "C" void kernel_launch(void* const* d_in, const int* in_sizes, int n_in,
                              void* d_out, int out_size, void* d_ws, size_t ws_size,
                              hipStream_t stream) {
    (void)in_sizes; (void)n_in; (void)out_size; (void)ws_size;
    const float* seqs  = (const float*)d_in[0];
    const float* ets   = (const float*)d_in[1];
    const int*   masks = (const int*)d_in[2];
    const float* Wf  = (const float*)d_in[3];
    const float* bf  = (const float*)d_in[4];
    const float* Wk  = (const float*)d_in[5];
    const float* bk  = (const float*)d_in[6];
    const float* Wq  = (const float*)d_in[7];
    const float* bq  = (const float*)d_in[8];
    const float* Wv  = (const float*)d_in[9];
    const float* bv  = (const float*)d_in[10];
    const float* Wih = (const float*)d_in[11];
    const float* Whh = (const float*)d_in[12];
    const float* bih = (const float*)d_in[13];
    const float* bhh = (const float*)d_in[14];
    const float* Wo  = (const float*)d_in[15];
    const float* bo  = (const float*)d_in[16];

    // ws layout: whF 256K | wiF 128K | ctx 26.2M  (attn tables in device globals)
    char* ws = (char*)d_ws;
    bf16x8* whF = (bf16x8*)(ws);
    bf16x8* wiF = (bf16x8*)(ws + 262144);
    float*  ctx = (float*) (ws + 262144 + 131072);

    hipLaunchKernelGGL(prep_all, dim3(52), dim3(512), 0, stream,
                       Wih, Whh, whF, wiF, Wf, bf, Wq, bq, Wv, Wk, bk);
    hipLaunchKernelGGL(edge_attn_ctx, dim3(4096), dim3(128), 0, stream,
                       seqs, ets, masks, bv, ctx);
    hipLaunchKernelGGL(lstm_mfma, dim3(256), dim3(512), 0, stream,
                       ctx, whF, wiF, bih, bhh, Wo, bo, (float*)d_out);
}

// Round 7
// 281.545 us; speedup vs baseline: 1.0159x; 1.0159x over previous
//
#include <hip/hip_runtime.h>
#include <math.h>

#define BS   2048
#define SEQ  50
#define NPOS (BS * SEQ)

typedef __attribute__((ext_vector_type(8))) short bf16x8;   // 8 bf16 = 4 VGPR
typedef __attribute__((ext_vector_type(4))) float f32x4;

__device__ __forceinline__ float sigf(float x) { return 1.0f / (1.0f + __expf(-x)); }
__device__ __forceinline__ float tanhfast(float x) {
    float e = __expf(2.0f * x);
    return 1.0f - 2.0f / (e + 1.0f);
}
__device__ __forceinline__ unsigned short bfrn(float x) {   // fp32 -> bf16 rne
    unsigned int u = __float_as_uint(x);
    u += 0x7FFFu + ((u >> 16) & 1u);
    return (unsigned short)(u >> 16);
}
__device__ __forceinline__ float bf2f(unsigned short h) {
    return __uint_as_float(((unsigned int)h) << 16);
}

#define FMA4(A, X, W) \
    A = fmaf((X).x, (W).x, A); A = fmaf((X).y, (W).y, A); \
    A = fmaf((X).z, (W).z, A); A = fmaf((X).w, (W).w, A);

// ---------------------------------------------------------------------------
// Precomputed attention tables (position-independent, HW-verified in R5):
//   Wvf[64][10]: Wv . Wf(:,0:10)
//   Ce [64][9]:  (Wf(:,10+e)+bf) . Wv
//   Ag [4][10][7]: g_h[k] = Ag[h][k][0:6].self6 + Ag[h][k][6]
//   Bd [9][4][7]:  dd[e][h] = Bd[e][h][0:6].self6 + Bd[e][h][6]
// Per position:  att[e][h] = 0.25*(raw10_e . g_h + dd[e][h]), softmax,
//                ctx[o] = (rbar_h . Wvf[o] + sum_e p Ce'[o][e]) (Ce' incl bv)
// ---------------------------------------------------------------------------
__device__ float Wvf_d[640];
__device__ float Ce_d[576];
__device__ float Ag_d[280];
__device__ float Bd_d[252];

// ---------------------------------------------------------------------------
// prep: blocks 0..47 build MFMA weight fragments; blocks 48..51 attn tables.
// ---------------------------------------------------------------------------
__global__ __launch_bounds__(512) void prep_all(
    const float* __restrict__ Wih, const float* __restrict__ Whh,
    bf16x8* __restrict__ whF, bf16x8* __restrict__ wiF,
    const float* __restrict__ Wf, const float* __restrict__ bf,
    const float* __restrict__ Wq, const float* __restrict__ bq,
    const float* __restrict__ Wv,
    const float* __restrict__ Wk, const float* __restrict__ bk)
{
    int id = blockIdx.x * 512 + threadIdx.x;
    if (id < 24576) {
        const float* src;
        bf16x8* dst;
        int p;
        if (id < 16384) {
            int l = id & 63, frag = id >> 6;        // 0..255
            p = frag & 1;
            int kc = (frag >> 1) & 3, ti = (frag >> 3) & 3, w = frag >> 5;
            int n  = (w + 8 * ti) * 16 + (l & 15);
            int k0 = kc * 32 + (l >> 4) * 8;
            src = &Whh[n * 128 + k0];
            dst = &whF[frag * 64 + l];
        } else {
            int id2 = id - 16384;
            int l = id2 & 63, frag = id2 >> 6;      // 0..127
            p = frag & 1;
            int kc = (frag >> 1) & 1, tile = frag >> 2;
            int n  = tile * 16 + (l & 15);
            int k0 = kc * 32 + (l >> 4) * 8;
            src = &Wih[n * 64 + k0];
            dst = &wiF[frag * 64 + l];
        }
        bf16x8 v;
        #pragma unroll
        for (int j = 0; j < 8; ++j) {
            float x = src[j];
            unsigned short hi = bfrn(x);
            unsigned short r  = p ? bfrn(x - bf2f(hi)) : hi;
            v[j] = (short)r;
        }
        *dst = v;
        return;
    }
    int i = id - 24576;
    if (i >= 1748) return;
    if (i < 640) {                       // Wvf[o][k]
        int o = i / 10, k = i % 10;
        float s = 0.f;
        #pragma unroll 8
        for (int j = 0; j < 64; ++j) s = fmaf(Wv[o * 64 + j], Wf[j * 19 + k], s);
        Wvf_d[i] = s;
    } else if (i < 1216) {               // Ce[o][e]
        int i2 = i - 640;
        int o = i2 / 9, e = i2 % 9;
        float s = 0.f;
        #pragma unroll 8
        for (int j = 0; j < 64; ++j)
            s = fmaf(Wf[j * 19 + 10 + e] + bf[j], Wv[o * 64 + j], s);
        Ce_d[i2] = s;
    } else if (i < 1496) {               // Ag[h][k][j]
        int i3 = i - 1216;               // 0..279
        int h = i3 / 70, rem = i3 % 70, k = rem / 7, j = rem % 7;
        float s = 0.f;
        for (int d = 0; d < 16; ++d) {
            int n = h * 16 + d;
            float Gnk = 0.f;
            #pragma unroll 8
            for (int mm = 0; mm < 64; ++mm)
                Gnk = fmaf(Wq[n * 64 + mm], Wf[mm * 19 + k], Gnk);
            float wkj = (j < 6) ? Wk[n * 6 + j] : bk[n];
            s = fmaf(wkj, Gnk, s);
        }
        Ag_d[i3] = s;
    } else {                             // Bd[e][h][j]
        int i4 = i - 1496;               // 0..251
        int e = i4 / 28, rem = i4 % 28, h = rem / 7, j = rem % 7;
        float s = 0.f;
        for (int d = 0; d < 16; ++d) {
            int n = h * 16 + d;
            float Den = bq[n];
            #pragma unroll 8
            for (int mm = 0; mm < 64; ++mm)
                Den = fmaf(Wf[mm * 19 + 10 + e] + bf[mm], Wq[n * 64 + mm], Den);
            float wkj = (j < 6) ? Wk[n * 6 + j] : bk[n];
            s = fmaf(wkj, Den, s);
        }
        Bd_d[i4] = s;
    }
}

// ---------------------------------------------------------------------------
// Kernel A v4: R4-v2 structure (64-thr blocks, __syncthreads — cheap on a
// 1-wave workgroup) + Ag/Bd key-fold (HW-verified R5): the key phase is gone
// (6 barriers/position, was 7), g/tt dot-products are 6 FMA (was 16), table
// registers 14 (was 32).
// ---------------------------------------------------------------------------
__global__ __launch_bounds__(64, 4) void edge_attn_ctx(
    const float* __restrict__ seqs,   // [BS,SEQ,3,3,6]
    const float* __restrict__ ets,    // [BS,SEQ,3,3,4]
    const int*   __restrict__ masks,  // [BS,SEQ,3,3]
    const float* __restrict__ bv,
    float* __restrict__ ctx)          // [BS,SEQ,64]
{
    const int o   = threadIdx.x;
    const int h_o = o >> 4;
    const int lg  = (o < 40) ? o : 0;     // g/rbar lanes: (gh, gk)
    const int gh  = lg / 10, gk = lg % 10;
    const int la  = (o < 36) ? o : 0;     // att lanes: (ah, ae)
    const int ah  = la / 9,  ae = la % 9;

    float Agr[7], Bdr[7];
    #pragma unroll
    for (int j = 0; j < 7; ++j) Agr[j] = Ag_d[(gh * 10 + gk) * 7 + j];
    #pragma unroll
    for (int j = 0; j < 7; ++j) Bdr[j] = Bd_d[(ae * 4 + ah) * 7 + j];
    float Wvfr[10];
    #pragma unroll
    for (int k = 0; k < 10; ++k) Wvfr[k] = Wvf_d[o * 10 + k];
    const float bvr = bv[o];
    float Cer[9];
    #pragma unroll
    for (int e = 0; e < 9; ++e) Cer[e] = Ce_d[o * 9 + e] + bvr;

    __shared__ float s_seq[54], s_et[36], s_g[40];
    __shared__ float s_att[36], s_exp[36], s_rbar[40];
    __shared__ int   s_mask[9];

    float r_seq = 0.f, r_et = 0.f; int r_mask = 0;
    {
        int p0 = blockIdx.x;
        if (o < 54) r_seq  = seqs[p0 * 54 + o];
        if (o < 36) r_et   = ets[p0 * 36 + o];
        if (o < 9)  r_mask = masks[p0 * 9 + o];
    }

    for (int p = blockIdx.x; p < NPOS; p += gridDim.x) {
        // ---- stage (from prefetched regs) ----
        if (o < 54) s_seq[o]  = r_seq;
        if (o < 36) s_et[o]   = r_et;
        if (o < 9)  s_mask[o] = r_mask;
        __syncthreads();

        // ---- issue next-position prefetch (spans 4 barriers) ----
        {
            int pn = p + gridDim.x;
            if (pn < NPOS) {
                if (o < 54) r_seq  = seqs[pn * 54 + o];
                if (o < 36) r_et   = ets[pn * 36 + o];
                if (o < 9)  r_mask = masks[pn * 9 + o];
            }
        }

        // ---- g (lanes<40) and dd (lanes<36) affine in self6 broadcast ----
        float c0 = s_seq[24], c1 = s_seq[25], c2 = s_seq[26],
              c3 = s_seq[27], c4 = s_seq[28], c5 = s_seq[29];
        float tt = 0.f;
        if (o < 40) {
            float g = Agr[6];
            g = fmaf(c0, Agr[0], g); g = fmaf(c1, Agr[1], g);
            g = fmaf(c2, Agr[2], g); g = fmaf(c3, Agr[3], g);
            g = fmaf(c4, Agr[4], g); g = fmaf(c5, Agr[5], g);
            s_g[o] = g;
        }
        if (o < 36) {
            tt = Bdr[6];
            tt = fmaf(c0, Bdr[0], tt); tt = fmaf(c1, Bdr[1], tt);
            tt = fmaf(c2, Bdr[2], tt); tt = fmaf(c3, Bdr[3], tt);
            tt = fmaf(c4, Bdr[4], tt); tt = fmaf(c5, Bdr[5], tt);
        }
        __syncthreads();

        // ---- att[e][h] (lanes<36) ----
        float a = 0.f;
        if (o < 36) {
            a = tt;
            #pragma unroll
            for (int k = 0; k < 6; ++k) a = fmaf(s_seq[ae * 6 + k], s_g[ah * 10 + k], a);
            #pragma unroll
            for (int k = 0; k < 4; ++k) a = fmaf(s_et[ae * 4 + k], s_g[ah * 10 + 6 + k], a);
            a *= 0.25f;
            if (s_mask[ae] == 0) a = -1.0e10f;
            s_att[o] = a;
        }
        __syncthreads();

        // ---- exp with per-head max (lanes<36) ----
        float ex = 0.f;
        if (o < 36) {
            float mx = s_att[ah * 9 + 0];
            #pragma unroll
            for (int e = 1; e < 9; ++e) mx = fmaxf(mx, s_att[ah * 9 + e]);
            ex = __expf(a - mx);
            s_exp[o] = ex;
        }
        __syncthreads();

        // ---- rbar (lanes<40, unnormalized) ----
        if (o < 40) {
            float rb = 0.f;
            #pragma unroll
            for (int e = 0; e < 9; ++e) {
                float x = (gk < 6) ? s_seq[e * 6 + gk] : s_et[e * 4 + (gk - 6)];
                rb = fmaf(s_exp[gh * 9 + e], x, rb);
            }
            s_rbar[o] = rb;
        }
        __syncthreads();

        // ---- ctx (all 64 lanes); normalize at the end ----
        {
            float ssum = 0.f;
            #pragma unroll
            for (int e = 0; e < 9; ++e) ssum += s_exp[h_o * 9 + e];
            float acc = 0.f;
            #pragma unroll
            for (int k = 0; k < 10; ++k) acc = fmaf(s_rbar[h_o * 10 + k], Wvfr[k], acc);
            #pragma unroll
            for (int e = 0; e < 9; ++e) acc = fmaf(s_exp[h_o * 9 + e], Cer[e], acc);
            ctx[p * 64 + o] = acc * (1.0f / ssum);
        }
        __syncthreads();
        // (trailing barrier protects s_seq/s_et reads in rbar phase of this
        //  iter from next iter's stage writes; ctx phase reads only sr/sx)
    }
}

// ---------------------------------------------------------------------------
// Kernel C v12: pair-step MFMA LSTM (unchanged from R4; 115-123 us).
// ---------------------------------------------------------------------------
#define MFMA16(A, B, C) __builtin_amdgcn_mfma_f32_16x16x32_bf16(A, B, C, 0, 0, 0)
#define MM4(F, W0, W1, W2, W3) \
    a0 = MFMA16(F, W0, a0); a1 = MFMA16(F, W1, a1); \
    a2 = MFMA16(F, W2, a2); a3 = MFMA16(F, W3, a3);

#define HPASS \
    MM4(hfh[0], whr[0][0][0], whr[1][0][0], whr[2][0][0], whr[3][0][0]) \
    MM4(hfh[1], whr[0][1][0], whr[1][1][0], whr[2][1][0], whr[3][1][0]) \
    MM4(hfh[2], whr[0][2][0], whr[1][2][0], whr[2][2][0], whr[3][2][0]) \
    MM4(hfh[3], whr[0][3][0], whr[1][3][0], whr[2][3][0], whr[3][3][0]) \
    MM4(hfl[0], whr[0][0][0], whr[1][0][0], whr[2][0][0], whr[3][0][0]) \
    MM4(hfl[1], whr[0][1][0], whr[1][1][0], whr[2][1][0], whr[3][1][0]) \
    MM4(hfl[2], whr[0][2][0], whr[1][2][0], whr[2][2][0], whr[3][2][0]) \
    MM4(hfl[3], whr[0][3][0], whr[1][3][0], whr[2][3][0], whr[3][3][0]) \
    MM4(hfh[0], whr[0][0][1], whr[1][0][1], whr[2][0][1], whr[3][0][1]) \
    MM4(hfh[1], whr[0][1][1], whr[1][1][1], whr[2][1][1], whr[3][1][1]) \
    MM4(hfh[2], whr[0][2][1], whr[1][2][1], whr[2][2][1], whr[3][2][1]) \
    MM4(hfh[3], whr[0][3][1], whr[1][3][1], whr[2][3][1], whr[3][3][1])

#define REDIST_E(ch, g0, g1) { \
    float s2_ = __shfl_xor(ch[2], 32), s3_ = __shfl_xor(ch[3], 32); \
    g0 = lolq ? ch[0] : s2_;  g1 = lolq ? ch[1] : s3_; }
#define REDIST_O(ch, g0, g1) { \
    float s0_ = __shfl_xor(ch[0], 32), s1_ = __shfl_xor(ch[1], 32); \
    g0 = lolq ? s0_ : ch[2];  g1 = lolq ? s1_ : ch[3]; }

#define PWBODY(gi0,gf0,gg0,go0,gi1,gf1,gg1,go1, WB0, WB1) { \
    float i0_ = sigf(gi0 + bi), f0_ = sigf(gf0 + bff); \
    float gA_ = tanhfast(gg0 + bg), o0_ = sigf(go0 + bo); \
    c20 = fmaf(f0_, c20, i0_ * gA_); \
    float hv0_ = o0_ * tanhfast(c20); \
    float i1_ = sigf(gi1 + bi), f1_ = sigf(gf1 + bff); \
    float gB_ = tanhfast(gg1 + bg), o1_ = sigf(go1 + bo); \
    c21 = fmaf(f1_, c21, i1_ * gB_); \
    float hv1_ = o1_ * tanhfast(c21); \
    unsigned short hh0_ = bfrn(hv0_), hh1_ = bfrn(hv1_); \
    unsigned short hl0_ = bfrn(hv0_ - bf2f(hh0_)), hl1_ = bfrn(hv1_ - bf2f(hh1_)); \
    *(unsigned short*)((char*)s_hh + (WB0)) = hh0_; \
    *(unsigned short*)((char*)s_hl + (WB0)) = hl0_; \
    *(unsigned short*)((char*)s_hh + (WB1)) = hh1_; \
    *(unsigned short*)((char*)s_hl + (WB1)) = hl1_; }

__global__ __launch_bounds__(512, 2) void lstm_mfma(
    const float*  __restrict__ ctx,    // [BS,SEQ,64]
    const bf16x8* __restrict__ whF,    // 16384 frags
    const bf16x8* __restrict__ wiFg,   // 8192 frags
    const float*  __restrict__ b_ih, const float* __restrict__ b_hh,
    const float*  __restrict__ W_out, const float* __restrict__ b_out,
    float* __restrict__ out)           // [BS,64]
{
    const int t  = threadIdx.x;
    const int w  = t >> 6, l = t & 63;
    const int lm = l & 15, lq = l >> 4;
    const int row0 = blockIdx.x * 8;            // 8 real rows per block

    __shared__ bf16x8 s_wi[8192];                       // 128 KB  W_ih frags
    __shared__ unsigned short s_xh[1024], s_xl[1024];   // [16][64] pair tile
    __shared__ unsigned short s_hh[4096], s_hl[4096];   // planes L(0B) H(4096B)

    for (int i = t; i < 8192; i += 512) s_wi[i] = wiFg[i];
    for (int i = t; i < 1024; i += 512) { s_xh[i] = 0; s_xl[i] = 0; }
    for (int i = t; i < 4096; i += 512) { s_hh[i] = 0; s_hl[i] = 0; }

    bf16x8 whr[4][4][2];
    #pragma unroll
    for (int ti = 0; ti < 4; ++ti)
        #pragma unroll
        for (int kc = 0; kc < 4; ++kc)
            #pragma unroll
            for (int p = 0; p < 2; ++p)
                whr[ti][kc][p] = whF[(((w * 4 + ti) * 4 + kc) * 2 + p) * 64 + l];

    const int m = w * 16 + lm;
    const float bi  = b_ih[m]       + b_hh[m];
    const float bff = b_ih[128 + m] + b_hh[128 + m];
    const float bg  = b_ih[256 + m] + b_hh[256 + m];
    const float bo  = b_ih[384 + m] + b_hh[384 + m];

    const int  urb  = ((lq & 1) << 2) | (lq & 2);
    const bool lolq = (lq < 2);
    float c20 = 0.f, c21 = 0.f;

    const int xrow  = t >> 5;
    const int xl32  = t & 31;
    const int srow  = xrow & 7;
    const int spair = xrow >> 3;
    const float2* ctx2 = (const float2*)ctx;
    const int xbase = (row0 + srow) * SEQ + spair;
    const int xwb   = xrow * 128 + ((4 * xl32) ^ ((xrow & 7) << 4));
    const int swzr  = (lm & 7) << 4;
    const int hwb_m = 32 * w + 2 * lm;
    const int wb0e = 4096 + (8 + urb) * 256 + (hwb_m ^ (urb << 4));
    const int wb1e = 4096 + (9 + urb) * 256 + (hwb_m ^ ((urb + 1) << 4));
    const int wb0o = urb * 256 + (hwb_m ^ (urb << 4));
    const int wb1o = (urb + 1) * 256 + (hwb_m ^ ((urb + 1) << 4));

    float2 xv = ctx2[xbase * 32 + xl32];

    for (int u = 0; u < SEQ / 2; ++u) {
        {   // stage x-pair (rows 0-7 = x(s0), rows 8-15 = x(s1))
            unsigned short xh0 = bfrn(xv.x), xh1 = bfrn(xv.y);
            unsigned short xl0 = bfrn(xv.x - bf2f(xh0)), xl1 = bfrn(xv.y - bf2f(xh1));
            *(unsigned int*)((char*)s_xh + xwb) = (unsigned int)xh0 | ((unsigned int)xh1 << 16);
            *(unsigned int*)((char*)s_xl + xwb) = (unsigned int)xl0 | ((unsigned int)xl1 << 16);
        }
        __syncthreads();   // x-pair + h(s0-1) (plane L) visible

        float2 xvn = make_float2(0.f, 0.f);
        if (u + 1 < SEQ / 2) xvn = ctx2[(xbase + 2 * u + 2) * 32 + xl32];

        bf16x8 hfh[4], hfl[4];
        if (u > 0) {
            #pragma unroll
            for (int kc = 0; kc < 4; ++kc) {
                int b = lm * 256 + ((kc * 64 + lq * 16) ^ swzr);   // plane L
                hfh[kc] = *(const bf16x8*)((const char*)s_hh + b);
                hfl[kc] = *(const bf16x8*)((const char*)s_hl + b);
            }
        }
        bf16x8 xfh[2], xfl[2];
        #pragma unroll
        for (int kc = 0; kc < 2; ++kc) {
            int b = lm * 128 + ((kc * 64 + lq * 16) ^ swzr);
            xfh[kc] = *(const bf16x8*)((const char*)s_xh + b);
            xfl[kc] = *(const bf16x8*)((const char*)s_xl + b);
        }

        f32x4 a0 = {0.f,0.f,0.f,0.f}, a1 = a0, a2 = a0, a3 = a0;

        if (u > 0) { HPASS }           // h(s0-1)W -> acc rows 0-7 only

        #pragma unroll                  // x-pass: both steps, junk-free
        for (int kc = 0; kc < 2; ++kc) {
            bf16x8 wihi[4], wilo[4];
            #pragma unroll
            for (int ti = 0; ti < 4; ++ti) {
                int base = (((w + 8 * ti) * 2 + kc) * 2) * 64 + l;
                wihi[ti] = s_wi[base];
                wilo[ti] = s_wi[base + 64];
            }
            MM4(xfh[kc], wihi[0], wihi[1], wihi[2], wihi[3])
            MM4(xfl[kc], wihi[0], wihi[1], wihi[2], wihi[3])
            MM4(xfh[kc], wilo[0], wilo[1], wilo[2], wilo[3])
        }

        {   // even pointwise: rows 0-7
            float gi0, gi1, gf0, gf1, gg0, gg1, go0, go1;
            REDIST_E(a0, gi0, gi1)
            REDIST_E(a1, gf0, gf1)
            REDIST_E(a2, gg0, gg1)
            REDIST_E(a3, go0, go1)
            PWBODY(gi0, gf0, gg0, go0, gi1, gf1, gg1, go1, wb0e, wb1e)
        }

        // ================= ODD step s1 = 2u+1 =================
        __syncthreads();   // h(s0) (plane H) visible
        #pragma unroll
        for (int kc = 0; kc < 4; ++kc) {
            int b = 4096 + lm * 256 + ((kc * 64 + lq * 16) ^ swzr);  // plane H
            hfh[kc] = *(const bf16x8*)((const char*)s_hh + b);
            hfl[kc] = *(const bf16x8*)((const char*)s_hl + b);
        }
        HPASS                          // h(s0)W -> acc rows 8-15 only

        {   // odd pointwise: rows 8-15
            float gi0, gi1, gf0, gf1, gg0, gg1, go0, go1;
            REDIST_O(a0, gi0, gi1)
            REDIST_O(a1, gf0, gf1)
            REDIST_O(a2, gg0, gg1)
            REDIST_O(a3, go0, go1)
            PWBODY(gi0, gf0, gg0, go0, gi1, gf1, gg1, go1, wb0o, wb1o)
        }
        xv = xvn;
    }
    __syncthreads();

    // ---- epilogue: h(SEQ-1)=h(49) is odd -> plane L rows 0-7 ----
    {
        const int row = t >> 5;
        if (row < 8) {
            const int j0 = t & 31, j1 = (t & 31) + 32;
            const int rswz = (row & 7) << 4;
            float accA = b_out[j0], accB = b_out[j1];
            #pragma unroll
            for (int kq = 0; kq < 16; ++kq) {
                int b = row * 256 + ((kq * 16) ^ rswz);
                bf16x8 hh8 = *(const bf16x8*)((const char*)s_hh + b);
                bf16x8 hl8 = *(const bf16x8*)((const char*)s_hl + b);
                #pragma unroll
                for (int e = 0; e < 8; ++e) {
                    float h = bf2f((unsigned short)hh8[e]) + bf2f((unsigned short)hl8[e]);
                    int k = kq * 8 + e;
                    accA = fmaf(h, W_out[j0 * 128 + k], accA);
                    accB = fmaf(h, W_out[j1 * 128 + k], accB);
                }
            }
            out[(row0 + row) * 64 + j0] = accA;
            out[(row0 + row) * 64 + j1] = accB;
        }
    }
}

// ---------------------------------------------------------------------------
extern "C" void kernel_launch(void* const* d_in, const int* in_sizes, int n_in,
                              void* d_out, int out_size, void* d_ws, size_t ws_size,
                              hipStream_t stream) {
    (void)in_sizes; (void)n_in; (void)out_size; (void)ws_size;
    const float* seqs  = (const float*)d_in[0];
    const float* ets   = (const float*)d_in[1];
    const int*   masks = (const int*)d_in[2];
    const float* Wf  = (const float*)d_in[3];
    const float* bf  = (const float*)d_in[4];
    const float* Wk  = (const float*)d_in[5];
    const float* bk  = (const float*)d_in[6];
    const float* Wq  = (const float*)d_in[7];
    const float* bq  = (const float*)d_in[8];
    const float* Wv  = (const float*)d_in[9];
    const float* bv  = (const float*)d_in[10];
    const float* Wih = (const float*)d_in[11];
    const float* Whh = (const float*)d_in[12];
    const float* bih = (const float*)d_in[13];
    const float* bhh = (const float*)d_in[14];
    const float* Wo  = (const float*)d_in[15];
    const float* bo  = (const float*)d_in[16];

    // ws layout: whF 256K | wiF 128K | ctx 26.2M  (attn tables in device globals)
    char* ws = (char*)d_ws;
    bf16x8* whF = (bf16x8*)(ws);
    bf16x8* wiF = (bf16x8*)(ws + 262144);
    float*  ctx = (float*) (ws + 262144 + 131072);

    hipLaunchKernelGGL(prep_all, dim3(52), dim3(512), 0, stream,
                       Wih, Whh, whF, wiF, Wf, bf, Wq, bq, Wv, Wk, bk);
    hipLaunchKernelGGL(edge_attn_ctx, dim3(4096), dim3(64), 0, stream,
                       seqs, ets, masks, bv, ctx);
    hipLaunchKernelGGL(lstm_mfma, dim3(256), dim3(512), 0, stream,
                       ctx, whF, wiF, bih, bhh, Wo, bo, (float*)d_out);
}